// Round 16
// baseline (439.567 us; speedup 1.0000x reference)
//
#include <hip/hip_runtime.h>

#define NN 100000
#define NE 3200000
#define DF 512
#define HID 16
#define NC 7
#define NBK 782     // buckets of 128 nodes
#define BCAP 6144   // per-bucket edge capacity bound
#define SC_B 640    // scatter blocks
#define SEDG 5000   // edges per scatter block (640*5000 = NE)
#define OFW 784     // offg row stride
#define GB 782      // gemm blocks: 4 waves = 2 row-groups x 2 k-slices

// ---------------- fused: coalesced bucket scatter + K-split SGPR GEMM ----------------
// Scatter blocks [0,SC_B): LDS counting-sort own 5000 edges by bucket, flush
// CONTIGUOUS 20KB segment + 783-entry offset row. No global atomics.
// GEMM blocks: lane=row, W1 wave-uniform (SGPR), K-split 2 -> h1p partials.
__global__ __launch_bounds__(256) void k_fused(const float* __restrict__ x,
                                               const float* __restrict__ W1,
                                               const int* __restrict__ src,
                                               const int* __restrict__ dst,
                                               float* __restrict__ h1p,
                                               int* __restrict__ seg,
                                               int* __restrict__ offg) {
    __shared__ int stage[SEDG];
    __shared__ int off[NBK + 1];
    __shared__ int part[256];
    __shared__ int cur[NBK];
    int tid = threadIdx.x;
    if (blockIdx.x < SC_B) {
        int blk = blockIdx.x;
        int e0 = blk * SEDG;
        for (int i = tid; i < NBK; i += 256) cur[i] = 0;
        __syncthreads();
        for (int e = e0 + tid; e < e0 + SEDG; e += 256) atomicAdd(&cur[dst[e] >> 7], 1);
        __syncthreads();
        {   // exclusive scan cur -> off
            int base = tid * 4;
            int sum = 0;
#pragma unroll
            for (int j = 0; j < 4; ++j) if (base + j < NBK) sum += cur[base + j];
            part[tid] = sum;
            __syncthreads();
            for (int s2 = 1; s2 < 256; s2 <<= 1) {
                int v = (tid >= s2) ? part[tid - s2] : 0;
                __syncthreads();
                part[tid] += v;
                __syncthreads();
            }
            int run = (tid > 0) ? part[tid - 1] : 0;
#pragma unroll
            for (int j = 0; j < 4; ++j) {
                int idx = base + j;
                if (idx < NBK) { off[idx] = run; run += cur[idx]; }
            }
            if (tid == 0) off[NBK] = SEDG;
        }
        __syncthreads();
        for (int i = tid; i < NBK; i += 256) cur[i] = off[i];
        __syncthreads();
        for (int e = e0 + tid; e < e0 + SEDG; e += 256) {
            int d = dst[e];
            int pos = atomicAdd(&cur[d >> 7], 1);  // LDS returning atomic
            stage[pos] = src[e] | ((d & 127) << 17);
        }
        __syncthreads();
        // coalesced flush: contiguous segment + offset row
        int* sp = seg + (size_t)blk * SEDG;
        for (int i = tid; i < SEDG; i += 256) sp[i] = stage[i];
        int* op = offg + (size_t)blk * OFW;
        for (int i = tid; i <= NBK; i += 256) op[i] = off[i];
        return;
    }
    // ---- GEMM role: lane = row, SGPR weights, K-split 2 ----
    int w = (blockIdx.x - SC_B) * 4 + (tid >> 6);
    int g = w >> 1, ks = w & 1;
    int lane = tid & 63;
    long row = (long)g * 64 + lane;
    long crow = row < NN ? row : NN - 1;
    const float4* xr = (const float4*)(x + crow * DF + ks * 256);
    const float* Wk = W1 + ks * 256 * HID;
    float acc[16];
#pragma unroll
    for (int i = 0; i < 16; ++i) acc[i] = 0.f;
#pragma unroll 2
    for (int c = 0; c < 64; ++c) {  // 64 float4 = 256 k's
        float4 xv = xr[c];
#pragma unroll
        for (int j = 0; j < 4; ++j) {
            float xs = (j == 0) ? xv.x : (j == 1) ? xv.y : (j == 2) ? xv.z : xv.w;
            int k = c * 4 + j;
#pragma unroll
            for (int col = 0; col < 16; ++col)
                acc[col] = fmaf(xs, Wk[k * HID + col], acc[col]);
        }
    }
    if (row < NN) {
        float* hp = h1p + (size_t)ks * NN * HID + row * HID;
#pragma unroll
        for (int q = 0; q < 4; ++q) {
            float4 o;
            o.x = acc[q * 4 + 0]; o.y = acc[q * 4 + 1];
            o.z = acc[q * 4 + 2]; o.w = acc[q * 4 + 3];
            *(float4*)(hp + q * 4) = o;
        }
    }
}

// ---------------- per-bucket degree + combine K-partials + prescale ----------------
__global__ __launch_bounds__(256) void k_deg(const int* __restrict__ seg,
                                             const int* __restrict__ offg,
                                             float* __restrict__ h1p) {
    __shared__ int hist[128];
    __shared__ float dl[128];
    int b = blockIdx.x, tid = threadIdx.x;
    if (tid < 128) hist[tid] = 0;
    __syncthreads();
    for (int r3 = 0; r3 < 3; ++r3) {
        int sblk = r3 * 256 + tid;
        if (sblk < SC_B) {
            int st = offg[(size_t)sblk * OFW + b];
            int en = offg[(size_t)sblk * OFW + b + 1];
            const int* sp = seg + (size_t)sblk * SEDG;
            for (int j = st; j < en; ++j) atomicAdd(&hist[sp[j] >> 17], 1);
        }
    }
    __syncthreads();
    if (tid < 128) dl[tid] = rsqrtf((float)hist[tid] + 1.0f);
    __syncthreads();
    // combine 2 partials + prescale by dinv (in place into partial 0)
    const float4* p1 = (const float4*)(h1p + (size_t)NN * HID);
    float4* p0 = (float4*)h1p;
    for (int i = tid; i < 512; i += 256) {
        int ln = i >> 2;
        int node = b * 128 + ln;
        if (node < NN) {
            float di = dl[ln];
            float4 a = p0[(size_t)node * 4 + (i & 3)];
            float4 c = p1[(size_t)node * 4 + (i & 3)];
            a.x = (a.x + c.x) * di; a.y = (a.y + c.y) * di;
            a.z = (a.z + c.z) * di; a.w = (a.w + c.w) * di;
            p0[(size_t)node * 4 + (i & 3)] = a;
        }
    }
}

// ---------------- layer-1: gather + LDS node-sort + register aggregate ----------------
__global__ __launch_bounds__(256) void k_agg1(const int* __restrict__ seg,
                                              const int* __restrict__ offg,
                                              const float* __restrict__ h1s,
                                              const float* __restrict__ b1,
                                              const float* __restrict__ W2,
                                              float* __restrict__ h2s) {
    __shared__ int sorted[BCAP];
    __shared__ int hist[128];
    __shared__ int off2[128];
    __shared__ int cur2[128];
    __shared__ float dl[128];
    int b = blockIdx.x, tid = threadIdx.x;
    if (tid < 128) hist[tid] = 0;
    __syncthreads();
    for (int r3 = 0; r3 < 3; ++r3) {  // pass 1: count
        int sblk = r3 * 256 + tid;
        if (sblk < SC_B) {
            int st = offg[(size_t)sblk * OFW + b];
            int en = offg[(size_t)sblk * OFW + b + 1];
            const int* sp = seg + (size_t)sblk * SEDG;
            for (int j = st; j < en; ++j) atomicAdd(&hist[sp[j] >> 17], 1);
        }
    }
    __syncthreads();
    if (tid < 128) off2[tid] = hist[tid];
    __syncthreads();
    for (int s2 = 1; s2 < 128; s2 <<= 1) {  // inclusive scan
        int u = 0;
        if (tid < 128 && tid >= s2) u = off2[tid - s2];
        __syncthreads();
        if (tid < 128) off2[tid] += u;
        __syncthreads();
    }
    if (tid < 128) {
        int start = off2[tid] - hist[tid];
        off2[tid] = start;
        cur2[tid] = start;
        dl[tid] = rsqrtf((float)hist[tid] + 1.0f);
    }
    __syncthreads();
    for (int r3 = 0; r3 < 3; ++r3) {  // pass 2: place
        int sblk = r3 * 256 + tid;
        if (sblk < SC_B) {
            int st = offg[(size_t)sblk * OFW + b];
            int en = offg[(size_t)sblk * OFW + b + 1];
            const int* sp = seg + (size_t)sblk * SEDG;
            for (int j = st; j < en; ++j) {
                int v = sp[j];
                int pos = atomicAdd(&cur2[v >> 17], 1);
                if (pos < BCAP) sorted[pos] = v & 0x1FFFF;
            }
        }
    }
    __syncthreads();
    int ch = tid & 15, g2 = tid >> 4;
    for (int it = 0; it < 8; ++it) {
        int ln = it * 16 + g2;
        int node = b * 128 + ln;
        int st = off2[ln];
        int end = min(st + hist[ln], BCAP);
        float a0 = 0.f, a1 = 0.f;
        int e = st;
        for (; e + 1 < end; e += 2) {
            int s0 = sorted[e], s1 = sorted[e + 1];  // LDS broadcast in group
            a0 += h1s[(size_t)s0 * HID + ch];
            a1 += h1s[(size_t)s1 * HID + ch];
        }
        if (e < end) a0 += h1s[(size_t)sorted[e] * HID + ch];
        if (node < NN) {
            float did = dl[ln];
            float acc = (a0 + a1 + h1s[(size_t)node * HID + ch]) * did + b1[ch];
            float hr = fmaxf(acc, 0.f);
            float hj = 0.f;
#pragma unroll
            for (int k = 0; k < HID; ++k) {
                float hk = __shfl(hr, k, 16);
                if (ch < NC) hj = fmaf(hk, W2[k * NC + ch], hj);
            }
            if (ch < NC) h2s[(size_t)node * NC + ch] = hj * did;
        } else {
            // keep shfl participation uniform: dummy
#pragma unroll
            for (int k = 0; k < HID; ++k) (void)__shfl(0.f, k, 16);
        }
    }
}

// ---------------- layer-2: gather + LDS node-sort + aggregate + log_softmax ----------------
__global__ __launch_bounds__(256) void k_agg2(const int* __restrict__ seg,
                                              const int* __restrict__ offg,
                                              const float* __restrict__ h2s,
                                              const float* __restrict__ b2,
                                              float* __restrict__ out) {
    __shared__ int sorted[BCAP];
    __shared__ int hist[128];
    __shared__ int off2[128];
    __shared__ int cur2[128];
    __shared__ float dl[128];
    int b = blockIdx.x, tid = threadIdx.x;
    if (tid < 128) hist[tid] = 0;
    __syncthreads();
    for (int r3 = 0; r3 < 3; ++r3) {
        int sblk = r3 * 256 + tid;
        if (sblk < SC_B) {
            int st = offg[(size_t)sblk * OFW + b];
            int en = offg[(size_t)sblk * OFW + b + 1];
            const int* sp = seg + (size_t)sblk * SEDG;
            for (int j = st; j < en; ++j) atomicAdd(&hist[sp[j] >> 17], 1);
        }
    }
    __syncthreads();
    if (tid < 128) off2[tid] = hist[tid];
    __syncthreads();
    for (int s2 = 1; s2 < 128; s2 <<= 1) {
        int u = 0;
        if (tid < 128 && tid >= s2) u = off2[tid - s2];
        __syncthreads();
        if (tid < 128) off2[tid] += u;
        __syncthreads();
    }
    if (tid < 128) {
        int start = off2[tid] - hist[tid];
        off2[tid] = start;
        cur2[tid] = start;
        dl[tid] = rsqrtf((float)hist[tid] + 1.0f);
    }
    __syncthreads();
    for (int r3 = 0; r3 < 3; ++r3) {
        int sblk = r3 * 256 + tid;
        if (sblk < SC_B) {
            int st = offg[(size_t)sblk * OFW + b];
            int en = offg[(size_t)sblk * OFW + b + 1];
            const int* sp = seg + (size_t)sblk * SEDG;
            for (int j = st; j < en; ++j) {
                int v = sp[j];
                int pos = atomicAdd(&cur2[v >> 17], 1);
                if (pos < BCAP) sorted[pos] = v & 0x1FFFF;
            }
        }
    }
    __syncthreads();
    int ch = tid & 7, g2 = tid >> 3;  // 32 groups of 8
    for (int it = 0; it < 4; ++it) {
        int ln = it * 32 + g2;
        int node = b * 128 + ln;
        int st = off2[ln];
        int end = min(st + hist[ln], BCAP);
        float a0 = 0.f, a1 = 0.f;
        int e = st;
        for (; e + 1 < end; e += 2) {
            int s0 = sorted[e], s1 = sorted[e + 1];
            if (ch < NC) {
                a0 += h2s[(size_t)s0 * NC + ch];
                a1 += h2s[(size_t)s1 * NC + ch];
            }
        }
        if (e < end && ch < NC) a0 += h2s[(size_t)sorted[e] * NC + ch];
        float o = -1e30f;
        if (ch < NC) o = (a0 + a1 + h2s[(size_t)node * NC + ch]) * dl[ln] + b2[ch];
        float m = o;
#pragma unroll
        for (int offm = 1; offm < 8; offm <<= 1) m = fmaxf(m, __shfl_xor(m, offm, 8));
        float ex = (ch < NC) ? expf(o - m) : 0.f;
        float s8 = ex;
#pragma unroll
        for (int offm = 1; offm < 8; offm <<= 1) s8 += __shfl_xor(s8, offm, 8);
        if (node < NN && ch < NC) out[(size_t)node * NC + ch] = o - m - logf(s8);
    }
}

extern "C" void kernel_launch(void* const* d_in, const int* in_sizes, int n_in,
                              void* d_out, int out_size, void* d_ws, size_t ws_size,
                              hipStream_t stream) {
    const float* x  = (const float*)d_in[0];
    const int*   ei = (const int*)d_in[1];
    const float* W1 = (const float*)d_in[2];
    const float* b1 = (const float*)d_in[3];
    const float* W2 = (const float*)d_in[4];
    const float* b2 = (const float*)d_in[5];
    float* out = (float*)d_out;

    const int* src = ei;       // edge_index[0]
    const int* dst = ei + NE;  // edge_index[1]

    // ws layout: [seg 640*5000 | offg 640*784 | h1p 2*16NN | h2 7NN]  ~= 30.4 MB
    int*   seg  = (int*)d_ws;
    int*   offg = seg + (size_t)SC_B * SEDG;
    float* h1p  = (float*)(offg + (size_t)SC_B * OFW);
    float* h2   = h1p + (size_t)2 * NN * HID;

    k_fused <<<SC_B + GB, 256, 0, stream>>>(x, W1, src, dst, h1p, seg, offg);
    k_deg   <<<NBK, 256, 0, stream>>>(seg, offg, h1p);
    k_agg1  <<<NBK, 256, 0, stream>>>(seg, offg, h1p, b1, W2, h2);
    k_agg2  <<<NBK, 256, 0, stream>>>(seg, offg, h2, b2, out);
}